// Round 8
// baseline (1434.732 us; speedup 1.0000x reference)
//
#include <hip/hip_runtime.h>
#include <hip/hip_bf16.h>
#include <math.h>
#include <stdint.h>

// Problem constants (SelectiveSSM: D_MODEL=1024, D_STATE=16, D_CONV=4, EXPAND=2)
#define B_SZ 4
#define T_SZ 2048
#define DM   1024
#define DI   2048          // D_INNER
#define DS   16            // D_STATE
#define BT   (B_SZ*T_SZ)   // 8192
#define NC   2304          // padded N for fused dt+ssm GEMM (9 x 256)

typedef __attribute__((ext_vector_type(8))) short short8;
typedef __attribute__((ext_vector_type(4))) float f32x4;

__device__ __forceinline__ float siluf(float v) { return v / (1.f + __expf(-v)); }
__device__ __forceinline__ float softplusf(float x) {
    return fmaxf(x, 0.f) + log1pf(__expf(-fabsf(x)));
}
__device__ __forceinline__ unsigned short f2b(float f) {
    __hip_bfloat16 h = __float2bfloat16(f);
    return *reinterpret_cast<unsigned short*>(&h);
}
__device__ __forceinline__ float b2f(unsigned short u) {
    unsigned v = (unsigned)u << 16;
    float f;
    __builtin_memcpy(&f, &v, 4);
    return f;
}
__device__ __forceinline__ void gld_lds16(const void* g, void* l) {
    __builtin_amdgcn_global_load_lds(
        (const __attribute__((address_space(1))) unsigned int*)g,
        (__attribute__((address_space(3))) unsigned int*)l,
        16, 0, 0);
}

// ---------------------------------------------------------------------------
// Merged fp32 -> bf16 conversions: x | W_in | W_out plain; W_dt/W_x packed
// into Wcb (2304 x 2048 with zero pad rows 2080..2303). One launch.
// ---------------------------------------------------------------------------
#define N4_X    (BT * DM / 4)        // 2097152
#define N4_WIN  (2 * DI * DM / 4)    // 1048576
#define N4_WOUT (DM * DI / 4)        // 524288
#define N4_WC   (NC * (DI / 4))      // 1179648
#define N4_TOT  (N4_X + N4_WIN + N4_WOUT + N4_WC)

__global__ __launch_bounds__(256)
void cvt_all(const float* __restrict__ x,   unsigned short* __restrict__ xb,
             const float* __restrict__ Win, unsigned short* __restrict__ Winb,
             const float* __restrict__ Wout,unsigned short* __restrict__ Woutb,
             const float* __restrict__ Wdt, const float* __restrict__ Wx,
             unsigned short* __restrict__ Wcb)
{
    int i = blockIdx.x * 256 + threadIdx.x;
    if (i >= N4_TOT) return;
    float4 v;
    ushort4* dst;
    if (i < N4_X) {
        v = ((const float4*)x)[i];
        dst = (ushort4*)xb + i;
    } else if (i < N4_X + N4_WIN) {
        const int j = i - N4_X;
        v = ((const float4*)Win)[j];
        dst = (ushort4*)Winb + j;
    } else if (i < N4_X + N4_WIN + N4_WOUT) {
        const int j = i - (N4_X + N4_WIN);
        v = ((const float4*)Wout)[j];
        dst = (ushort4*)Woutb + j;
    } else {
        const int j = i - (N4_X + N4_WIN + N4_WOUT);
        const int row = j >> 9;            // / (2048/4)
        const int c4  = j & 511;
        if (row < 2048)      v = ((const float4*)Wdt)[(size_t)row * 512 + c4];
        else if (row < 2080) v = ((const float4*)Wx)[(size_t)(row - 2048) * 512 + c4];
        else                 v = make_float4(0.f, 0.f, 0.f, 0.f);
        dst = (ushort4*)Wcb + j;
    }
    ushort4 o;
    o.x = f2b(v.x); o.y = f2b(v.y); o.z = f2b(v.z); o.w = f2b(v.w);
    *dst = o;
}

// ---------------------------------------------------------------------------
// bf16 MFMA GEMM 256x256 (v8 geometry, REGISTER CAP FIXED):
// v8's __launch_bounds__(512,2) forced a 128-VGPR/thread cap (2nd arg = min
// waves/SIMD; 16 waves/CU) -> acc[8][4]=128 regs was scratch-allocated ->
// 2.27 GB spill writes. This version uses __launch_bounds__(512) (1 block/CU,
// 256 VGPR budget; est ~210 used). Addressing/swizzle identical to v8,
// which PASSED correctness (absmax 0.082) -> low risk.
// 256x256 tile, BK=64, 512 thr / 8 waves (2Mx4N), 128x64 per wave (acc[8][4]).
// Sync: verified v5/v7 2-phase skeleton (STAGE next, ONE __syncthreads/iter).
// LDS 2 x (A 32KB + B 32KB) = 128 KiB -> 1 block/CU.
// Staging bytes/FLOP: 16 B/KFLOP (half of 128^2's 32) -- the tile-size lever.
//
// Swizzle (verified 0-conflict v7): 128B rows; phys = l ^ (((l>>7)&7)<<4);
// linear gld_lds dest + inverse-swizzled global source granule
//   sgran = (tid&7) ^ ((tid>>3)&7)    ((row&7) invariant under +64k rows).
//
// mode 0: bf16 split store  cols<2048 -> o0, else -> o1 (both ldc 2048)
// mode 1: cols<2048 -> softplus(v+bias[col]) fp32 o0 (ldc 2048);
//         2048..2063 -> o1[row*16+c]; 2064..2079 -> o2[row*16+c]; >=2080 drop
// Requires: M%256==0, N%256==0, K%64==0, K/64>=2.
// ---------------------------------------------------------------------------
__global__ __launch_bounds__(512)
void gemm_mfma256(const unsigned short* __restrict__ A,
                  const unsigned short* __restrict__ Bm,
                  int M, int N, int K, int mode,
                  const float* __restrict__ bias,
                  void* __restrict__ o0, void* __restrict__ o1, void* __restrict__ o2)
{
    __shared__ unsigned short As[2][256 * 64];   // 2 x 32 KB
    __shared__ unsigned short Bs[2][256 * 64];   // 2 x 32 KB

    // GROUP_M swizzle (GM=8 divides npm=32 for both GEMMs here)
    const int npn = N >> 8;
    const int pid = blockIdx.x;
    const int gsz = 8 * npn;
    const int gid = pid / gsz;
    const int pm  = gid * 8 + (pid % 8);
    const int pn  = (pid % gsz) / 8;
    const int bm  = pm * 256;
    const int bn  = pn * 256;

    const int tid  = threadIdx.x;
    const int lane = tid & 63;
    const int wave = tid >> 6;          // 0..7
    const int wm   = (wave >> 2) * 128; // {0,128}
    const int wn   = (wave & 3) * 64;   // {0,64,128,192}

    f32x4 zero4 = {0.f, 0.f, 0.f, 0.f};
    f32x4 acc[8][4];
#pragma unroll
    for (int i = 0; i < 8; i++)
#pragma unroll
        for (int j = 0; j < 4; j++) acc[i][j] = zero4;

    // staging: 512 threads x 16B = 8 KiB/round; a 256x64 bf16 tile (32 KiB)
    // in 4 rounds (rows +0,+64,+128,+192). LDS dest LINEAR; global source
    // granule inverse-swizzled (rule #21).
    const int sr    = tid >> 3;                      // 0..63
    const int sgran = (tid & 7) ^ ((tid >> 3) & 7);  // inverse of read swizzle
    const unsigned short* Ag = A  + (size_t)(bm + sr) * K + sgran * 8;
    const unsigned short* Bg = Bm + (size_t)(bn + sr) * K + sgran * 8;
    const size_t rowK64 = (size_t)64 * K;            // +64 rows

    // per-lane swizzled read byte-offsets: frags [m or n][kk], kk=0,1
    const int fr = lane & 15;          // row within 16-tile
    const int fg = lane >> 4;          // 16B k-granule 0..3 (kk adds 4)
    int aoff[8][2], boff[4][2];
#pragma unroll
    for (int i = 0; i < 8; i++)
#pragma unroll
        for (int kk = 0; kk < 2; kk++) {
            const int l = (wm + i * 16 + fr) * 128 + (fg + 4 * kk) * 16;
            aoff[i][kk] = l ^ (((l >> 7) & 7) << 4);
        }
#pragma unroll
    for (int j = 0; j < 4; j++)
#pragma unroll
        for (int kk = 0; kk < 2; kk++) {
            const int l = (wn + j * 16 + fr) * 128 + (fg + 4 * kk) * 16;
            boff[j][kk] = l ^ (((l >> 7) & 7) << 4);
        }

#define STAGE(buf, kbase) do {                                              \
        const size_t kb_ = (size_t)(kbase);                                 \
        gld_lds16(Ag + kb_,               &As[(buf)][tid * 8]);             \
        gld_lds16(Ag + rowK64 + kb_,      &As[(buf)][4096  + tid * 8]);     \
        gld_lds16(Ag + 2 * rowK64 + kb_,  &As[(buf)][8192  + tid * 8]);     \
        gld_lds16(Ag + 3 * rowK64 + kb_,  &As[(buf)][12288 + tid * 8]);     \
        gld_lds16(Bg + kb_,               &Bs[(buf)][tid * 8]);             \
        gld_lds16(Bg + rowK64 + kb_,      &Bs[(buf)][4096  + tid * 8]);     \
        gld_lds16(Bg + 2 * rowK64 + kb_,  &Bs[(buf)][8192  + tid * 8]);     \
        gld_lds16(Bg + 3 * rowK64 + kb_,  &Bs[(buf)][12288 + tid * 8]);     \
    } while (0)

    // prologue: stage k-tile 0 into buf 0
    STAGE(0, 0);
    __syncthreads();

    int cur = 0;
    for (int k0 = 0; k0 < K; k0 += 64) {
        // prefetch next K-tile into the other buffer (async, drains at barrier)
        if (k0 + 64 < K) STAGE(cur ^ 1, k0 + 64);

        const char* Ab = (const char*)&As[cur][0];
        const char* Bb = (const char*)&Bs[cur][0];
#pragma unroll
        for (int kk = 0; kk < 2; kk++) {
            short8 af[8], bf[4];
#pragma unroll
            for (int i = 0; i < 8; i++)
                af[i] = *(const short8*)(Ab + aoff[i][kk]);
#pragma unroll
            for (int j = 0; j < 4; j++)
                bf[j] = *(const short8*)(Bb + boff[j][kk]);
            __builtin_amdgcn_s_setprio(1);
#pragma unroll
            for (int i = 0; i < 8; i++)
#pragma unroll
                for (int j = 0; j < 4; j++)
                    acc[i][j] = __builtin_amdgcn_mfma_f32_16x16x32_bf16(
                        af[i], bf[j], acc[i][j], 0, 0, 0);
            __builtin_amdgcn_s_setprio(0);
        }
        __syncthreads();   // waits prefetch (vmcnt) + all reads of cur done
        cur ^= 1;
    }
#undef STAGE

    // epilogue. C/D layout: col = lane&15, row = (lane>>4)*4 + r  [m89/m91]
    const int cr0 = bm + wm + fg * 4;
    const int cc0 = bn + wn + fr;
#pragma unroll
    for (int i = 0; i < 8; i++) {
#pragma unroll
        for (int j = 0; j < 4; j++) {
            const int col = cc0 + j * 16;
#pragma unroll
            for (int r = 0; r < 4; r++) {
                const int row = cr0 + i * 16 + r;
                float v = acc[i][j][r];
                if (mode == 0) {
                    if (col < 2048)
                        ((unsigned short*)o0)[(size_t)row * 2048 + col] = f2b(v);
                    else
                        ((unsigned short*)o1)[(size_t)row * 2048 + col - 2048] = f2b(v);
                } else {   // mode 1
                    if (col < 2048) {
                        ((float*)o0)[(size_t)row * 2048 + col] = softplusf(v + bias[col]);
                    } else if (col < 2064) {
                        ((float*)o1)[(size_t)row * DS + (col - 2048)] = v;
                    } else if (col < 2080) {
                        ((float*)o2)[(size_t)row * DS + (col - 2064)] = v;
                    }
                }
            }
        }
    }
}

// ---------------------------------------------------------------------------
// bf16 MFMA GEMM 128x128 (v5, verified): used for G6 (N=1024 -> 512 blocks
// at 128^2 vs only 128 at 256^2). mode 2: fp32 plain store, ldc = N.
// ---------------------------------------------------------------------------
__global__ __launch_bounds__(512)
void gemm_mfma(const unsigned short* __restrict__ A,
               const unsigned short* __restrict__ Bm,
               int M, int N, int K, int mode,
               const float* __restrict__ bias,
               void* __restrict__ o0, void* __restrict__ o1, void* __restrict__ o2)
{
    __shared__ unsigned short As[2][128 * 32];   // 2 x 8 KB
    __shared__ unsigned short Bs[2][128 * 32];   // 2 x 8 KB

    const int npn = N >> 7;
    const int pid = blockIdx.x;
    const int gsz = 16 * npn;
    const int gid = pid / gsz;
    const int pm  = gid * 16 + (pid % 16);
    const int pn  = (pid % gsz) / 16;
    const int bm  = pm * 128;
    const int bn  = pn * 128;

    const int tid  = threadIdx.x;
    const int lane = tid & 63;
    const int wave = tid >> 6;          // 0..7
    const int wm   = (wave >> 2) * 64;  // {0,64}
    const int wn   = (wave & 3) * 32;   // {0,32,64,96}

    f32x4 zero4 = {0.f, 0.f, 0.f, 0.f};
    f32x4 acc[4][2];
#pragma unroll
    for (int i = 0; i < 4; i++)
#pragma unroll
        for (int j = 0; j < 2; j++) acc[i][j] = zero4;

    const int sr    = tid >> 2;                      // 0..127
    const int sgran = (tid & 3) ^ ((tid >> 3) & 3);  // inverse of read swizzle
    const unsigned short* Ag = A  + (size_t)(bm + sr) * K + sgran * 8;
    const unsigned short* Bg = Bm + (size_t)(bn + sr) * K + sgran * 8;

    const int fr = lane & 15;
    const int fg = lane >> 4;
    int aoff[4], boff[2];
#pragma unroll
    for (int i = 0; i < 4; i++) {
        const int l = (wm + i * 16 + fr) * 64 + fg * 16;
        aoff[i] = l ^ (((l >> 7) & 3) << 4);
    }
#pragma unroll
    for (int j = 0; j < 2; j++) {
        const int l = (wn + j * 16 + fr) * 64 + fg * 16;
        boff[j] = l ^ (((l >> 7) & 3) << 4);
    }

    gld_lds16(Ag, &As[0][tid * 8]);
    gld_lds16(Bg, &Bs[0][tid * 8]);
    __syncthreads();

    int cur = 0;
    for (int k0 = 0; k0 < K; k0 += 32) {
        if (k0 + 32 < K) {
            gld_lds16(Ag + k0 + 32, &As[cur ^ 1][tid * 8]);
            gld_lds16(Bg + k0 + 32, &Bs[cur ^ 1][tid * 8]);
        }
        const char* Ab = (const char*)&As[cur][0];
        const char* Bb = (const char*)&Bs[cur][0];
        short8 af[4], bf[2];
#pragma unroll
        for (int i = 0; i < 4; i++)
            af[i] = *(const short8*)(Ab + aoff[i]);
#pragma unroll
        for (int j = 0; j < 2; j++)
            bf[j] = *(const short8*)(Bb + boff[j]);
#pragma unroll
        for (int i = 0; i < 4; i++)
#pragma unroll
            for (int j = 0; j < 2; j++)
                acc[i][j] = __builtin_amdgcn_mfma_f32_16x16x32_bf16(
                    af[i], bf[j], acc[i][j], 0, 0, 0);
        __syncthreads();
        cur ^= 1;
    }

    const int cr0 = bm + wm + (lane >> 4) * 4;
    const int cc0 = bn + wn + (lane & 15);
#pragma unroll
    for (int i = 0; i < 4; i++) {
#pragma unroll
        for (int j = 0; j < 2; j++) {
            const int col = cc0 + j * 16;
#pragma unroll
            for (int r = 0; r < 4; r++) {
                const int row = cr0 + i * 16 + r;
                float v = acc[i][j][r];
                if (mode == 0) {
                    if (col < 2048)
                        ((unsigned short*)o0)[(size_t)row * 2048 + col] = f2b(v);
                    else
                        ((unsigned short*)o1)[(size_t)row * 2048 + col - 2048] = f2b(v);
                } else if (mode == 1) {
                    if (col < 2048) {
                        ((float*)o0)[(size_t)row * 2048 + col] = softplusf(v + bias[col]);
                    } else if (col < 2064) {
                        ((float*)o1)[(size_t)row * DS + (col - 2048)] = v;
                    } else if (col < 2080) {
                        ((float*)o2)[(size_t)row * DS + (col - 2064)] = v;
                    }
                } else {
                    ((float*)o0)[(size_t)row * N + col] = v;
                }
            }
        }
    }
}

// ---------------------------------------------------------------------------
// Depthwise causal conv (width 4) + SiLU, bf16 in -> bf16 out.
// Vectorized 8 channels/thread (short8 loads, G13). One block = one (b,t)
// row (256 thr x 8 ch = 2048 = DI), so tap guards are uniform.
// ---------------------------------------------------------------------------
__global__ __launch_bounds__(256)
void conv_silu(const unsigned short* __restrict__ xpb, const float* __restrict__ cw,
               const float* __restrict__ cb, unsigned short* __restrict__ xcb)
{
    const int bt  = blockIdx.x;            // 0..BT-1
    const int t   = bt & (T_SZ - 1);
    const int i0  = threadIdx.x * 8;       // channel group base

    float acc[8];
    {
        float4 c0 = ((const float4*)cb)[threadIdx.x * 2];
        float4 c1 = ((const float4*)cb)[threadIdx.x * 2 + 1];
        acc[0]=c0.x; acc[1]=c0.y; acc[2]=c0.z; acc[3]=c0.w;
        acc[4]=c1.x; acc[5]=c1.y; acc[6]=c1.z; acc[7]=c1.w;
    }
    float4 w[8];
#pragma unroll
    for (int c = 0; c < 8; c++) w[c] = ((const float4*)cw)[i0 + c];

#pragma unroll
    for (int k = 0; k < 4; k++) {
        const int tt = t - 3 + k;          // uniform across block
        if (tt >= 0) {
            short8 xv = *(const short8*)(xpb + (size_t)(bt - 3 + k) * DI + i0);
#pragma unroll
            for (int c = 0; c < 8; c++)
                acc[c] = fmaf(b2f((unsigned short)xv[c]), ((const float*)&w[c])[k], acc[c]);
        }
    }
    short8 o;
#pragma unroll
    for (int c = 0; c < 8; c++) o[c] = (short)f2b(siluf(acc[c]));
    *(short8*)(xcb + (size_t)bt * DI + i0) = o;
}

// ---------------------------------------------------------------------------
// Chunked parallel selective scan. Block: 16 chunks x 16 d-cols = 256 thr.
// Grid: (DI/16, B). Phase1: per-chunk (h_end, prod dA) from h0=0.
// Phase2: LDS carry combine. Phase3: replay with corrected h0, y in-place.
// FAST PATH: A[s] = -(s+1)/2 (this problem's A_log) -> exp(dv*A[s]) =
// r^(s+1), r = exp(-dv/2): 1 exp + 15 muls. Runtime-checked, general
// fallback kept.
// ---------------------------------------------------------------------------
#define CH 16
#define CL (T_SZ / CH)   // 128

__global__ __launch_bounds__(256)
void scan2(const unsigned short* __restrict__ xcb, float* __restrict__ dty,
           const float* __restrict__ Bp, const float* __restrict__ Cp,
           const float* __restrict__ A_log)
{
    __shared__ float shH[CH][16][DS];
    __shared__ float shP[CH][16][DS];
    __shared__ float shI[CH][16][DS];
    const int tid = threadIdx.x;
    const int c = tid >> 4;
    const int g = tid & 15;
    const int b = blockIdx.y;
    const int d = blockIdx.x * 16 + g;

    float A[DS];
    bool structured = true;
#pragma unroll
    for (int s = 0; s < DS; s++) {
        A[s] = -__expf(A_log[s]);
        structured = structured && (fabsf(A[s] + 0.5f * (float)(s + 1)) <= 1e-4f);
    }

    const size_t colbase = (size_t)b * T_SZ * DI + d;
    const unsigned short* xp = xcb + colbase + (size_t)c * CL * DI;
    float* dp = dty + colbase + (size_t)c * CL * DI;
    const float4* Bb = (const float4*)(Bp + ((size_t)b * T_SZ + c * CL) * DS);
    const float4* Cb = (const float4*)(Cp + ((size_t)b * T_SZ + c * CL) * DS);

    float h[DS];
    float sdv = 0.f;
#pragma unroll
    for (int s = 0; s < DS; s++) h[s] = 0.f;

    if (structured) {
        for (int i = 0; i < CL; i++) {
            const float xv = b2f(xp[(size_t)i * DI]);
            const float dv = dp[(size_t)i * DI];
            float4 Bv[4] = {Bb[i*4+0], Bb[i*4+1], Bb[i*4+2], Bb[i*4+3]};
            const float* bs = (const float*)&Bv[0];
            const float dx = dv * xv;
            sdv += dv;
            const float r = __expf(-0.5f * dv);
            float dA = r;
#pragma unroll
            for (int s = 0; s < DS; s++) {
                h[s] = fmaf(dA, h[s], dx * bs[s]);
                dA *= r;
            }
        }
    } else {
        for (int i = 0; i < CL; i++) {
            const float xv = b2f(xp[(size_t)i * DI]);
            const float dv = dp[(size_t)i * DI];
            float4 Bv[4] = {Bb[i*4+0], Bb[i*4+1], Bb[i*4+2], Bb[i*4+3]};
            const float* bs = (const float*)&Bv[0];
            const float dx = dv * xv;
            sdv += dv;
#pragma unroll
            for (int s = 0; s < DS; s++) {
                const float dA = __expf(dv * A[s]);
                h[s] = fmaf(dA, h[s], dx * bs[s]);
            }
        }
    }

    {
        float P[DS];
        if (structured) {
            const float R = __expf(-0.5f * sdv);
            float p = 1.f;
#pragma unroll
            for (int s = 0; s < DS; s++) { p *= R; P[s] = p; }
        } else {
#pragma unroll
            for (int s = 0; s < DS; s++) P[s] = __expf(sdv * A[s]);
        }
#pragma unroll
        for (int s = 0; s < DS; s += 4) {
            *(float4*)&shH[c][g][s] = make_float4(h[s], h[s+1], h[s+2], h[s+3]);
            *(float4*)&shP[c][g][s] = make_float4(P[s], P[s+1], P[s+2], P[s+3]);
        }
    }
    __syncthreads();

    {
        const int g2 = tid >> 4, s2 = tid & 15;
        float hin = 0.f;
        shI[0][g2][s2] = 0.f;
        for (int cc = 1; cc < CH; cc++) {
            hin = fmaf(shP[cc-1][g2][s2], hin, shH[cc-1][g2][s2]);
            shI[cc][g2][s2] = hin;
        }
    }
    __syncthreads();

#pragma unroll
    for (int s = 0; s < DS; s++) h[s] = shI[c][g][s];

    if (structured) {
        for (int i = 0; i < CL; i++) {
            const float xv = b2f(xp[(size_t)i * DI]);
            const float dv = dp[(size_t)i * DI];
            float4 Bv[4] = {Bb[i*4+0], Bb[i*4+1], Bb[i*4+2], Bb[i*4+3]};
            float4 Cv[4] = {Cb[i*4+0], Cb[i*4+1], Cb[i*4+2], Cb[i*4+3]};
            const float* bs = (const float*)&Bv[0];
            const float* cs = (const float*)&Cv[0];
            const float dx = dv * xv;
            float yv = 0.f;
            const float r = __expf(-0.5f * dv);
            float dA = r;
#pragma unroll
            for (int s = 0; s < DS; s++) {
                h[s] = fmaf(dA, h[s], dx * bs[s]);
                yv = fmaf(h[s], cs[s], yv);
                dA *= r;
            }
            dp[(size_t)i * DI] = yv;   // overwrites dt[t] after its last use
        }
    } else {
        for (int i = 0; i < CL; i++) {
            const float xv = b2f(xp[(size_t)i * DI]);
            const float dv = dp[(size_t)i * DI];
            float4 Bv[4] = {Bb[i*4+0], Bb[i*4+1], Bb[i*4+2], Bb[i*4+3]};
            float4 Cv[4] = {Cb[i*4+0], Cb[i*4+1], Cb[i*4+2], Cb[i*4+3]};
            const float* bs = (const float*)&Bv[0];
            const float* cs = (const float*)&Cv[0];
            const float dx = dv * xv;
            float yv = 0.f;
#pragma unroll
            for (int s = 0; s < DS; s++) {
                const float dA = __expf(dv * A[s]);
                h[s] = fmaf(dA, h[s], dx * bs[s]);
                yv = fmaf(h[s], cs[s], yv);
            }
            dp[(size_t)i * DI] = yv;
        }
    }
}

// ---------------------------------------------------------------------------
// Fused LayerNorm + xc*D residual + silu(z) gate. y fp32 in, yb bf16 out.
// Wave-level __shfl reduce (1 barrier), float4/short8 IO.
// ---------------------------------------------------------------------------
__global__ __launch_bounds__(256)
void ln_fuse(const float* __restrict__ y, const unsigned short* __restrict__ xcb,
             const unsigned short* __restrict__ zb, const float* __restrict__ g,
             const float* __restrict__ bln, const float* __restrict__ Dp,
             unsigned short* __restrict__ yb)
{
    __shared__ float pS[4], pSS[4];
    const int bt   = blockIdx.x;
    const int tid  = threadIdx.x;
    const int lane = tid & 63;
    const int wv   = tid >> 6;
    const float4* yr4 = (const float4*)(y + (size_t)bt * DI);
    const unsigned short* xr = xcb + (size_t)bt * DI;
    const unsigned short* zr = zb + (size_t)bt * DI;
    unsigned short* orow = yb + (size_t)bt * DI;

    float4 a = yr4[tid * 2];
    float4 b4 = yr4[tid * 2 + 1];
    float v[8] = {a.x, a.y, a.z, a.w, b4.x, b4.y, b4.z, b4.w};
    float s = 0.f, ss = 0.f;
#pragma unroll
    for (int j = 0; j < 8; j++) { s += v[j]; ss += v[j] * v[j]; }
#pragma unroll
    for (int off = 32; off > 0; off >>= 1) {
        s  += __shfl_down(s, off);
        ss += __shfl_down(ss, off);
    }
    if (lane == 0) { pS[wv] = s; pSS[wv] = ss; }
    __syncthreads();
    const float S  = pS[0] + pS[1] + pS[2] + pS[3];
    const float SS = pSS[0] + pSS[1] + pSS[2] + pSS[3];
    const float mu   = S * (1.f / DI);
    const float var  = SS * (1.f / DI) - mu * mu;
    const float rstd = rsqrtf(var + 1e-5f);

    const int d0 = tid * 8;
    float4 g0 = ((const float4*)g)[tid * 2],   g1 = ((const float4*)g)[tid * 2 + 1];
    float4 l0 = ((const float4*)bln)[tid * 2], l1 = ((const float4*)bln)[tid * 2 + 1];
    float4 D0 = ((const float4*)Dp)[tid * 2],  D1 = ((const float4*)Dp)[tid * 2 + 1];
    const float gg[8] = {g0.x, g0.y, g0.z, g0.w, g1.x, g1.y, g1.z, g1.w};
    const float ll[8] = {l0.x, l0.y, l0.z, l0.w, l1.x, l1.y, l1.z, l1.w};
    const float DD[8] = {D0.x, D0.y, D0.z, D0.w, D1.x, D1.y, D1.z, D1.w};
    short8 xv = *(const short8*)(xr + d0);
    short8 zv = *(const short8*)(zr + d0);
    short8 o;
#pragma unroll
    for (int j = 0; j < 8; j++) {
        float yn = (v[j] - mu) * rstd * gg[j] + ll[j];
        yn += b2f((unsigned short)xv[j]) * DD[j];
        yn *= siluf(b2f((unsigned short)zv[j]));
        o[j] = (short)f2b(yn);
    }
    *(short8*)(orow + d0) = o;
}

// ---------------------------------------------------------------------------
// Workspace layout (MiB offsets, total ~175 MiB):
//   [  0, 32)  xpb bf16  (G1 out) -> dead after conv -> yb bf16 (ln out)
//   [ 32, 64)  zb  bf16
//   [ 64, 96)  xcb bf16
//   [ 96,160)  dts fp32 (G3 out) -> y fp32 (scan, in-place)
//       [ 96,112) xb bf16   (dead before G3 writes dts)
//       [112,120) W_inb bf16 (dead before G3)
//   [160,170)  Wcb bf16 (2304x2048: W_dt | W_x | zeros) = 9.44 MiB
//   [170,174)  W_outb bf16
//   [174,175)  Bp, Cp fp32
// ---------------------------------------------------------------------------
extern "C" void kernel_launch(void* const* d_in, const int* in_sizes, int n_in,
                              void* d_out, int out_size, void* d_ws, size_t ws_size,
                              hipStream_t stream)
{
    const float* x      = (const float*)d_in[0];
    const float* W_in   = (const float*)d_in[1];
    const float* conv_w = (const float*)d_in[2];
    const float* conv_b = (const float*)d_in[3];
    const float* W_x    = (const float*)d_in[4];
    const float* W_dt   = (const float*)d_in[5];
    const float* b_dt   = (const float*)d_in[6];
    const float* A_log  = (const float*)d_in[7];
    const float* D_par  = (const float*)d_in[8];
    const float* W_out  = (const float*)d_in[9];
    const float* ln_g   = (const float*)d_in[10];
    const float* ln_b   = (const float*)d_in[11];
    float* out = (float*)d_out;

    char* w = (char*)d_ws;
    const size_t MB = 1ull << 20;
    unsigned short* xpb    = (unsigned short*)(w);
    unsigned short* zb     = (unsigned short*)(w + 32 * MB);
    unsigned short* xcb    = (unsigned short*)(w + 64 * MB);
    float*          dts    = (float*)(w + 96 * MB);
    unsigned short* xb     = (unsigned short*)(w + 96 * MB);
    unsigned short* W_inb  = (unsigned short*)(w + 112 * MB);
    unsigned short* Wcb    = (unsigned short*)(w + 160 * MB);
    unsigned short* W_outb = (unsigned short*)(w + 170 * MB);
    float*          BpF    = (float*)(w + 174 * MB);
    float*          CpF    = BpF + (size_t)BT * DS;
    unsigned short* yb     = xpb;   // reuse after conv

    dim3 blk(256);
    dim3 blk512(512);

    // merged conversions to bf16 (one launch)
    cvt_all<<<dim3((N4_TOT + 255) / 256), blk, 0, stream>>>(
        x, xb, W_in, W_inb, W_out, W_outb, W_dt, W_x, Wcb);

    // 1) xz = x @ W_in^T -> split bf16 xpb | zb  (256^2: grid 32x16=512)
    gemm_mfma256<<<dim3((BT / 256) * (2 * DI / 256)), blk512, 0, stream>>>(
        xb, W_inb, BT, 2 * DI, DM, 0, nullptr, xpb, zb, nullptr);

    // 2) depthwise conv + silu -> xcb bf16  (one block per (b,t) row)
    conv_silu<<<dim3(BT), blk, 0, stream>>>(xpb, conv_w, conv_b, xcb);

    // 3) fused dt+ssm GEMM (256^2: grid 32x9=288) -> dts fp32, Bp, Cp
    gemm_mfma256<<<dim3((BT / 256) * (NC / 256)), blk512, 0, stream>>>(
        xcb, Wcb, BT, NC, DI, 1, b_dt, dts, BpF, CpF);

    // 4) chunked parallel scan -> y fp32 (in-place over dts)
    scan2<<<dim3(DI / 16, B_SZ), blk, 0, stream>>>(xcb, dts, BpF, CpF, A_log);

    // 5) LayerNorm + residual + gate -> yb bf16
    ln_fuse<<<dim3(BT), blk, 0, stream>>>(dts, xcb, zb, ln_g, ln_b, D_par, yb);

    // 6) out = y @ W_out^T -> fp32 (128^2 kernel: N=1024 keeps 512 blocks)
    gemm_mfma<<<dim3((BT / 128) * (DM / 128)), blk512, 0, stream>>>(
        yb, W_outb, BT, DM, DI, 2, nullptr, out, nullptr, nullptr);
}

// Round 9
// 699.059 us; speedup vs baseline: 2.0524x; 2.0524x over previous
//
#include <hip/hip_runtime.h>
#include <hip/hip_bf16.h>
#include <math.h>
#include <stdint.h>

// Problem constants (SelectiveSSM: D_MODEL=1024, D_STATE=16, D_CONV=4, EXPAND=2)
#define B_SZ 4
#define T_SZ 2048
#define DM   1024
#define DI   2048          // D_INNER
#define DS   16            // D_STATE
#define BT   (B_SZ*T_SZ)   // 8192
#define NC   2304          // padded N for fused dt+ssm GEMM (9 x 256)

typedef __attribute__((ext_vector_type(8))) short short8;
typedef __attribute__((ext_vector_type(4))) float f32x4;

__device__ __forceinline__ float siluf(float v) { return v / (1.f + __expf(-v)); }
__device__ __forceinline__ float softplusf(float x) {
    return fmaxf(x, 0.f) + log1pf(__expf(-fabsf(x)));
}
__device__ __forceinline__ unsigned short f2b(float f) {
    __hip_bfloat16 h = __float2bfloat16(f);
    return *reinterpret_cast<unsigned short*>(&h);
}
__device__ __forceinline__ float b2f(unsigned short u) {
    unsigned v = (unsigned)u << 16;
    float f;
    __builtin_memcpy(&f, &v, 4);
    return f;
}
__device__ __forceinline__ void gld_lds16(const void* g, void* l) {
    __builtin_amdgcn_global_load_lds(
        (const __attribute__((address_space(1))) unsigned int*)g,
        (__attribute__((address_space(3))) unsigned int*)l,
        16, 0, 0);
}

// ---------------------------------------------------------------------------
// Merged fp32 -> bf16 conversions: x | W_in | W_out plain; W_dt/W_x packed
// into Wcb (2304 x 2048 with zero pad rows 2080..2303). One launch.
// ---------------------------------------------------------------------------
#define N4_X    (BT * DM / 4)        // 2097152
#define N4_WIN  (2 * DI * DM / 4)    // 1048576
#define N4_WOUT (DM * DI / 4)        // 524288
#define N4_WC   (NC * (DI / 4))      // 1179648
#define N4_TOT  (N4_X + N4_WIN + N4_WOUT + N4_WC)

__global__ __launch_bounds__(256)
void cvt_all(const float* __restrict__ x,   unsigned short* __restrict__ xb,
             const float* __restrict__ Win, unsigned short* __restrict__ Winb,
             const float* __restrict__ Wout,unsigned short* __restrict__ Woutb,
             const float* __restrict__ Wdt, const float* __restrict__ Wx,
             unsigned short* __restrict__ Wcb)
{
    int i = blockIdx.x * 256 + threadIdx.x;
    if (i >= N4_TOT) return;
    float4 v;
    ushort4* dst;
    if (i < N4_X) {
        v = ((const float4*)x)[i];
        dst = (ushort4*)xb + i;
    } else if (i < N4_X + N4_WIN) {
        const int j = i - N4_X;
        v = ((const float4*)Win)[j];
        dst = (ushort4*)Winb + j;
    } else if (i < N4_X + N4_WIN + N4_WOUT) {
        const int j = i - (N4_X + N4_WIN);
        v = ((const float4*)Wout)[j];
        dst = (ushort4*)Woutb + j;
    } else {
        const int j = i - (N4_X + N4_WIN + N4_WOUT);
        const int row = j >> 9;            // / (2048/4)
        const int c4  = j & 511;
        if (row < 2048)      v = ((const float4*)Wdt)[(size_t)row * 512 + c4];
        else if (row < 2080) v = ((const float4*)Wx)[(size_t)(row - 2048) * 512 + c4];
        else                 v = make_float4(0.f, 0.f, 0.f, 0.f);
        dst = (ushort4*)Wcb + j;
    }
    ushort4 o;
    o.x = f2b(v.x); o.y = f2b(v.y); o.z = f2b(v.z); o.w = f2b(v.w);
    *dst = o;
}

// ---------------------------------------------------------------------------
// bf16 MFMA GEMM 256x256 v3 -- NAMED ACCUMULATORS.
// v8/v11 post-mortem: f32x4 acc[8][4] (512B aggregate, 32 vector elems)
// exceeds the AMDGPU promote-alloca/SROA threshold -> the WHOLE accumulator
// lived in scratch (WRITE_SIZE 2.27 GB, identical under two launch_bounds
// settings => not an RA budget issue). Fix: 32 individually NAMED f32x4
// registers (no alloca exists), macro-generated MFMA + epilogue.
// Geometry/addressing byte-identical to v8/v11 (both PASSED correctness):
// 256x256 tile, BK=64, 512 thr / 8 waves (2Mx4N), 128x64 per wave.
// Sync: verified v5/v7 2-phase skeleton (STAGE next, ONE __syncthreads/iter).
// LDS 2 x (A 32KB + B 32KB) = 128 KiB -> 1 block/CU.
// __launch_bounds__(512,2): 2 waves/EU min = exactly 1 block/CU -> RA budget
// 256 VGPR/thread (est. use ~210).
// Swizzle (verified 0-conflict): 128B rows; phys = l ^ (((l>>7)&7)<<4);
// linear gld_lds dest + inverse-swizzled global source granule
//   sgran = (tid&7) ^ ((tid>>3)&7).
// mode 0: bf16 split store  cols<2048 -> o0, else -> o1 (both ldc 2048)
// mode 1: cols<2048 -> softplus(v+bias[col]) fp32 o0 (ldc 2048);
//         2048..2063 -> o1[row*16+c]; 2064..2079 -> o2[row*16+c]; >=2080 drop
// Requires: M%256==0, N%256==0, K%64==0, K/64>=2.
// ---------------------------------------------------------------------------
__device__ __forceinline__ void epi_store(f32x4 vv, int row0, int col, int mode,
                                          const float* __restrict__ bias,
                                          void* __restrict__ o0,
                                          void* __restrict__ o1,
                                          void* __restrict__ o2)
{
#pragma unroll
    for (int r = 0; r < 4; r++) {
        const int row = row0 + r;
        const float v = vv[r];
        if (mode == 0) {
            if (col < 2048)
                ((unsigned short*)o0)[(size_t)row * 2048 + col] = f2b(v);
            else
                ((unsigned short*)o1)[(size_t)row * 2048 + col - 2048] = f2b(v);
        } else {   // mode 1
            if (col < 2048) {
                ((float*)o0)[(size_t)row * 2048 + col] = softplusf(v + bias[col]);
            } else if (col < 2064) {
                ((float*)o1)[(size_t)row * DS + (col - 2048)] = v;
            } else if (col < 2080) {
                ((float*)o2)[(size_t)row * DS + (col - 2064)] = v;
            }
        }
    }
}

__global__ __launch_bounds__(512, 2)
void gemm_mfma256(const unsigned short* __restrict__ A,
                  const unsigned short* __restrict__ Bm,
                  int M, int N, int K, int mode,
                  const float* __restrict__ bias,
                  void* __restrict__ o0, void* __restrict__ o1, void* __restrict__ o2)
{
    __shared__ unsigned short As[2][256 * 64];   // 2 x 32 KB
    __shared__ unsigned short Bs[2][256 * 64];   // 2 x 32 KB

    // GROUP_M swizzle (GM=8 divides npm=32 for both GEMMs here)
    const int npn = N >> 8;
    const int pid = blockIdx.x;
    const int gsz = 8 * npn;
    const int gid = pid / gsz;
    const int pm  = gid * 8 + (pid % 8);
    const int pn  = (pid % gsz) / 8;
    const int bm  = pm * 256;
    const int bn  = pn * 256;

    const int tid  = threadIdx.x;
    const int lane = tid & 63;
    const int wave = tid >> 6;          // 0..7
    const int wm   = (wave >> 2) * 128; // {0,128}
    const int wn   = (wave & 3) * 64;   // {0,64,128,192}

    const f32x4 zero4 = {0.f, 0.f, 0.f, 0.f};
    // 32 NAMED accumulators (no alloca -> guaranteed registers)
    f32x4 c00=zero4,c01=zero4,c02=zero4,c03=zero4;
    f32x4 c10=zero4,c11=zero4,c12=zero4,c13=zero4;
    f32x4 c20=zero4,c21=zero4,c22=zero4,c23=zero4;
    f32x4 c30=zero4,c31=zero4,c32=zero4,c33=zero4;
    f32x4 c40=zero4,c41=zero4,c42=zero4,c43=zero4;
    f32x4 c50=zero4,c51=zero4,c52=zero4,c53=zero4;
    f32x4 c60=zero4,c61=zero4,c62=zero4,c63=zero4;
    f32x4 c70=zero4,c71=zero4,c72=zero4,c73=zero4;

    // staging: 512 threads x 16B = 8 KiB/round; a 256x64 bf16 tile (32 KiB)
    // in 4 rounds (rows +0,+64,+128,+192). LDS dest LINEAR; global source
    // granule inverse-swizzled (rule #21).
    const int sr    = tid >> 3;                      // 0..63
    const int sgran = (tid & 7) ^ ((tid >> 3) & 7);  // inverse of read swizzle
    const unsigned short* Ag = A  + (size_t)(bm + sr) * K + sgran * 8;
    const unsigned short* Bg = Bm + (size_t)(bn + sr) * K + sgran * 8;
    const size_t rowK64 = (size_t)64 * K;            // +64 rows

    // per-lane swizzled read byte-offsets: frags [m or n][kk], kk=0,1
    const int fr = lane & 15;          // row within 16-tile
    const int fg = lane >> 4;          // 16B k-granule 0..3 (kk adds 4)
    int aoff[8][2], boff[4][2];
#pragma unroll
    for (int i = 0; i < 8; i++)
#pragma unroll
        for (int kk = 0; kk < 2; kk++) {
            const int l = (wm + i * 16 + fr) * 128 + (fg + 4 * kk) * 16;
            aoff[i][kk] = l ^ (((l >> 7) & 7) << 4);
        }
#pragma unroll
    for (int j = 0; j < 4; j++)
#pragma unroll
        for (int kk = 0; kk < 2; kk++) {
            const int l = (wn + j * 16 + fr) * 128 + (fg + 4 * kk) * 16;
            boff[j][kk] = l ^ (((l >> 7) & 7) << 4);
        }

#define STAGE(buf, kbase) do {                                              \
        const size_t kb_ = (size_t)(kbase);                                 \
        gld_lds16(Ag + kb_,               &As[(buf)][tid * 8]);             \
        gld_lds16(Ag + rowK64 + kb_,      &As[(buf)][4096  + tid * 8]);     \
        gld_lds16(Ag + 2 * rowK64 + kb_,  &As[(buf)][8192  + tid * 8]);     \
        gld_lds16(Ag + 3 * rowK64 + kb_,  &As[(buf)][12288 + tid * 8]);     \
        gld_lds16(Bg + kb_,               &Bs[(buf)][tid * 8]);             \
        gld_lds16(Bg + rowK64 + kb_,      &Bs[(buf)][4096  + tid * 8]);     \
        gld_lds16(Bg + 2 * rowK64 + kb_,  &Bs[(buf)][8192  + tid * 8]);     \
        gld_lds16(Bg + 3 * rowK64 + kb_,  &Bs[(buf)][12288 + tid * 8]);     \
    } while (0)

#define MM_ROW(I) \
    c##I##0 = __builtin_amdgcn_mfma_f32_16x16x32_bf16(af[I], bf[0], c##I##0, 0, 0, 0); \
    c##I##1 = __builtin_amdgcn_mfma_f32_16x16x32_bf16(af[I], bf[1], c##I##1, 0, 0, 0); \
    c##I##2 = __builtin_amdgcn_mfma_f32_16x16x32_bf16(af[I], bf[2], c##I##2, 0, 0, 0); \
    c##I##3 = __builtin_amdgcn_mfma_f32_16x16x32_bf16(af[I], bf[3], c##I##3, 0, 0, 0);

    // prologue: stage k-tile 0 into buf 0
    STAGE(0, 0);
    __syncthreads();

    int cur = 0;
    for (int k0 = 0; k0 < K; k0 += 64) {
        // prefetch next K-tile into the other buffer (async, drains at barrier)
        if (k0 + 64 < K) STAGE(cur ^ 1, k0 + 64);

        const char* Ab = (const char*)&As[cur][0];
        const char* Bb = (const char*)&Bs[cur][0];
#pragma unroll
        for (int kk = 0; kk < 2; kk++) {
            short8 af[8], bf[4];
#pragma unroll
            for (int i = 0; i < 8; i++)
                af[i] = *(const short8*)(Ab + aoff[i][kk]);
#pragma unroll
            for (int j = 0; j < 4; j++)
                bf[j] = *(const short8*)(Bb + boff[j][kk]);
            __builtin_amdgcn_s_setprio(1);
            MM_ROW(0) MM_ROW(1) MM_ROW(2) MM_ROW(3)
            MM_ROW(4) MM_ROW(5) MM_ROW(6) MM_ROW(7)
            __builtin_amdgcn_s_setprio(0);
        }
        __syncthreads();   // waits prefetch (vmcnt) + all reads of cur done
        cur ^= 1;
    }
#undef STAGE
#undef MM_ROW

    // epilogue. C/D layout: col = lane&15, row = (lane>>4)*4 + r  [m89/m91]
    const int cr0 = bm + wm + fg * 4;
    const int cc0 = bn + wn + fr;
#define EPI(I) \
    epi_store(c##I##0, cr0 + (I)*16, cc0 +  0, mode, bias, o0, o1, o2); \
    epi_store(c##I##1, cr0 + (I)*16, cc0 + 16, mode, bias, o0, o1, o2); \
    epi_store(c##I##2, cr0 + (I)*16, cc0 + 32, mode, bias, o0, o1, o2); \
    epi_store(c##I##3, cr0 + (I)*16, cc0 + 48, mode, bias, o0, o1, o2);
    EPI(0) EPI(1) EPI(2) EPI(3) EPI(4) EPI(5) EPI(6) EPI(7)
#undef EPI
}

// ---------------------------------------------------------------------------
// bf16 MFMA GEMM 128x128 (v5, verified): used for G6 (N=1024 -> 512 blocks
// at 128^2 vs only 128 at 256^2). mode 2: fp32 plain store, ldc = N.
// ---------------------------------------------------------------------------
__global__ __launch_bounds__(512)
void gemm_mfma(const unsigned short* __restrict__ A,
               const unsigned short* __restrict__ Bm,
               int M, int N, int K, int mode,
               const float* __restrict__ bias,
               void* __restrict__ o0, void* __restrict__ o1, void* __restrict__ o2)
{
    __shared__ unsigned short As[2][128 * 32];   // 2 x 8 KB
    __shared__ unsigned short Bs[2][128 * 32];   // 2 x 8 KB

    const int npn = N >> 7;
    const int pid = blockIdx.x;
    const int gsz = 16 * npn;
    const int gid = pid / gsz;
    const int pm  = gid * 16 + (pid % 16);
    const int pn  = (pid % gsz) / 16;
    const int bm  = pm * 128;
    const int bn  = pn * 128;

    const int tid  = threadIdx.x;
    const int lane = tid & 63;
    const int wave = tid >> 6;          // 0..7
    const int wm   = (wave >> 2) * 64;  // {0,64}
    const int wn   = (wave & 3) * 32;   // {0,32,64,96}

    f32x4 zero4 = {0.f, 0.f, 0.f, 0.f};
    f32x4 acc[4][2];
#pragma unroll
    for (int i = 0; i < 4; i++)
#pragma unroll
        for (int j = 0; j < 2; j++) acc[i][j] = zero4;

    const int sr    = tid >> 2;                      // 0..127
    const int sgran = (tid & 3) ^ ((tid >> 3) & 3);  // inverse of read swizzle
    const unsigned short* Ag = A  + (size_t)(bm + sr) * K + sgran * 8;
    const unsigned short* Bg = Bm + (size_t)(bn + sr) * K + sgran * 8;

    const int fr = lane & 15;
    const int fg = lane >> 4;
    int aoff[4], boff[2];
#pragma unroll
    for (int i = 0; i < 4; i++) {
        const int l = (wm + i * 16 + fr) * 64 + fg * 16;
        aoff[i] = l ^ (((l >> 7) & 3) << 4);
    }
#pragma unroll
    for (int j = 0; j < 2; j++) {
        const int l = (wn + j * 16 + fr) * 64 + fg * 16;
        boff[j] = l ^ (((l >> 7) & 3) << 4);
    }

    gld_lds16(Ag, &As[0][tid * 8]);
    gld_lds16(Bg, &Bs[0][tid * 8]);
    __syncthreads();

    int cur = 0;
    for (int k0 = 0; k0 < K; k0 += 32) {
        if (k0 + 32 < K) {
            gld_lds16(Ag + k0 + 32, &As[cur ^ 1][tid * 8]);
            gld_lds16(Bg + k0 + 32, &Bs[cur ^ 1][tid * 8]);
        }
        const char* Ab = (const char*)&As[cur][0];
        const char* Bb = (const char*)&Bs[cur][0];
        short8 af[4], bf[2];
#pragma unroll
        for (int i = 0; i < 4; i++)
            af[i] = *(const short8*)(Ab + aoff[i]);
#pragma unroll
        for (int j = 0; j < 2; j++)
            bf[j] = *(const short8*)(Bb + boff[j]);
#pragma unroll
        for (int i = 0; i < 4; i++)
#pragma unroll
            for (int j = 0; j < 2; j++)
                acc[i][j] = __builtin_amdgcn_mfma_f32_16x16x32_bf16(
                    af[i], bf[j], acc[i][j], 0, 0, 0);
        __syncthreads();
        cur ^= 1;
    }

    const int cr0 = bm + wm + (lane >> 4) * 4;
    const int cc0 = bn + wn + (lane & 15);
#pragma unroll
    for (int i = 0; i < 4; i++) {
#pragma unroll
        for (int j = 0; j < 2; j++) {
            const int col = cc0 + j * 16;
#pragma unroll
            for (int r = 0; r < 4; r++) {
                const int row = cr0 + i * 16 + r;
                float v = acc[i][j][r];
                if (mode == 0) {
                    if (col < 2048)
                        ((unsigned short*)o0)[(size_t)row * 2048 + col] = f2b(v);
                    else
                        ((unsigned short*)o1)[(size_t)row * 2048 + col - 2048] = f2b(v);
                } else if (mode == 1) {
                    if (col < 2048) {
                        ((float*)o0)[(size_t)row * 2048 + col] = softplusf(v + bias[col]);
                    } else if (col < 2064) {
                        ((float*)o1)[(size_t)row * DS + (col - 2048)] = v;
                    } else if (col < 2080) {
                        ((float*)o2)[(size_t)row * DS + (col - 2064)] = v;
                    }
                } else {
                    ((float*)o0)[(size_t)row * N + col] = v;
                }
            }
        }
    }
}

// ---------------------------------------------------------------------------
// Depthwise causal conv (width 4) + SiLU, bf16 in -> bf16 out.
// Vectorized 8 channels/thread (short8 loads, G13). One block = one (b,t)
// row (256 thr x 8 ch = 2048 = DI), so tap guards are uniform.
// ---------------------------------------------------------------------------
__global__ __launch_bounds__(256)
void conv_silu(const unsigned short* __restrict__ xpb, const float* __restrict__ cw,
               const float* __restrict__ cb, unsigned short* __restrict__ xcb)
{
    const int bt  = blockIdx.x;            // 0..BT-1
    const int t   = bt & (T_SZ - 1);
    const int i0  = threadIdx.x * 8;       // channel group base

    float acc[8];
    {
        float4 c0 = ((const float4*)cb)[threadIdx.x * 2];
        float4 c1 = ((const float4*)cb)[threadIdx.x * 2 + 1];
        acc[0]=c0.x; acc[1]=c0.y; acc[2]=c0.z; acc[3]=c0.w;
        acc[4]=c1.x; acc[5]=c1.y; acc[6]=c1.z; acc[7]=c1.w;
    }
    float4 w[8];
#pragma unroll
    for (int c = 0; c < 8; c++) w[c] = ((const float4*)cw)[i0 + c];

#pragma unroll
    for (int k = 0; k < 4; k++) {
        const int tt = t - 3 + k;          // uniform across block
        if (tt >= 0) {
            short8 xv = *(const short8*)(xpb + (size_t)(bt - 3 + k) * DI + i0);
#pragma unroll
            for (int c = 0; c < 8; c++)
                acc[c] = fmaf(b2f((unsigned short)xv[c]), ((const float*)&w[c])[k], acc[c]);
        }
    }
    short8 o;
#pragma unroll
    for (int c = 0; c < 8; c++) o[c] = (short)f2b(siluf(acc[c]));
    *(short8*)(xcb + (size_t)bt * DI + i0) = o;
}

// ---------------------------------------------------------------------------
// Chunked parallel selective scan. Block: 16 chunks x 16 d-cols = 256 thr.
// Grid: (DI/16, B). Phase1: per-chunk (h_end, prod dA) from h0=0.
// Phase2: LDS carry combine. Phase3: replay with corrected h0, y in-place.
// FAST PATH: A[s] = -(s+1)/2 (this problem's A_log) -> exp(dv*A[s]) =
// r^(s+1), r = exp(-dv/2): 1 exp + 15 muls. Runtime-checked, general
// fallback kept.
// ---------------------------------------------------------------------------
#define CH 16
#define CL (T_SZ / CH)   // 128

__global__ __launch_bounds__(256)
void scan2(const unsigned short* __restrict__ xcb, float* __restrict__ dty,
           const float* __restrict__ Bp, const float* __restrict__ Cp,
           const float* __restrict__ A_log)
{
    __shared__ float shH[CH][16][DS];
    __shared__ float shP[CH][16][DS];
    __shared__ float shI[CH][16][DS];
    const int tid = threadIdx.x;
    const int c = tid >> 4;
    const int g = tid & 15;
    const int b = blockIdx.y;
    const int d = blockIdx.x * 16 + g;

    float A[DS];
    bool structured = true;
#pragma unroll
    for (int s = 0; s < DS; s++) {
        A[s] = -__expf(A_log[s]);
        structured = structured && (fabsf(A[s] + 0.5f * (float)(s + 1)) <= 1e-4f);
    }

    const size_t colbase = (size_t)b * T_SZ * DI + d;
    const unsigned short* xp = xcb + colbase + (size_t)c * CL * DI;
    float* dp = dty + colbase + (size_t)c * CL * DI;
    const float4* Bb = (const float4*)(Bp + ((size_t)b * T_SZ + c * CL) * DS);
    const float4* Cb = (const float4*)(Cp + ((size_t)b * T_SZ + c * CL) * DS);

    float h[DS];
    float sdv = 0.f;
#pragma unroll
    for (int s = 0; s < DS; s++) h[s] = 0.f;

    if (structured) {
        for (int i = 0; i < CL; i++) {
            const float xv = b2f(xp[(size_t)i * DI]);
            const float dv = dp[(size_t)i * DI];
            float4 Bv[4] = {Bb[i*4+0], Bb[i*4+1], Bb[i*4+2], Bb[i*4+3]};
            const float* bs = (const float*)&Bv[0];
            const float dx = dv * xv;
            sdv += dv;
            const float r = __expf(-0.5f * dv);
            float dA = r;
#pragma unroll
            for (int s = 0; s < DS; s++) {
                h[s] = fmaf(dA, h[s], dx * bs[s]);
                dA *= r;
            }
        }
    } else {
        for (int i = 0; i < CL; i++) {
            const float xv = b2f(xp[(size_t)i * DI]);
            const float dv = dp[(size_t)i * DI];
            float4 Bv[4] = {Bb[i*4+0], Bb[i*4+1], Bb[i*4+2], Bb[i*4+3]};
            const float* bs = (const float*)&Bv[0];
            const float dx = dv * xv;
            sdv += dv;
#pragma unroll
            for (int s = 0; s < DS; s++) {
                const float dA = __expf(dv * A[s]);
                h[s] = fmaf(dA, h[s], dx * bs[s]);
            }
        }
    }

    {
        float P[DS];
        if (structured) {
            const float R = __expf(-0.5f * sdv);
            float p = 1.f;
#pragma unroll
            for (int s = 0; s < DS; s++) { p *= R; P[s] = p; }
        } else {
#pragma unroll
            for (int s = 0; s < DS; s++) P[s] = __expf(sdv * A[s]);
        }
#pragma unroll
        for (int s = 0; s < DS; s += 4) {
            *(float4*)&shH[c][g][s] = make_float4(h[s], h[s+1], h[s+2], h[s+3]);
            *(float4*)&shP[c][g][s] = make_float4(P[s], P[s+1], P[s+2], P[s+3]);
        }
    }
    __syncthreads();

    {
        const int g2 = tid >> 4, s2 = tid & 15;
        float hin = 0.f;
        shI[0][g2][s2] = 0.f;
        for (int cc = 1; cc < CH; cc++) {
            hin = fmaf(shP[cc-1][g2][s2], hin, shH[cc-1][g2][s2]);
            shI[cc][g2][s2] = hin;
        }
    }
    __syncthreads();

#pragma unroll
    for (int s = 0; s < DS; s++) h[s] = shI[c][g][s];

    if (structured) {
        for (int i = 0; i < CL; i++) {
            const float xv = b2f(xp[(size_t)i * DI]);
            const float dv = dp[(size_t)i * DI];
            float4 Bv[4] = {Bb[i*4+0], Bb[i*4+1], Bb[i*4+2], Bb[i*4+3]};
            float4 Cv[4] = {Cb[i*4+0], Cb[i*4+1], Cb[i*4+2], Cb[i*4+3]};
            const float* bs = (const float*)&Bv[0];
            const float* cs = (const float*)&Cv[0];
            const float dx = dv * xv;
            float yv = 0.f;
            const float r = __expf(-0.5f * dv);
            float dA = r;
#pragma unroll
            for (int s = 0; s < DS; s++) {
                h[s] = fmaf(dA, h[s], dx * bs[s]);
                yv = fmaf(h[s], cs[s], yv);
                dA *= r;
            }
            dp[(size_t)i * DI] = yv;   // overwrites dt[t] after its last use
        }
    } else {
        for (int i = 0; i < CL; i++) {
            const float xv = b2f(xp[(size_t)i * DI]);
            const float dv = dp[(size_t)i * DI];
            float4 Bv[4] = {Bb[i*4+0], Bb[i*4+1], Bb[i*4+2], Bb[i*4+3]};
            float4 Cv[4] = {Cb[i*4+0], Cb[i*4+1], Cb[i*4+2], Cb[i*4+3]};
            const float* bs = (const float*)&Bv[0];
            const float* cs = (const float*)&Cv[0];
            const float dx = dv * xv;
            float yv = 0.f;
#pragma unroll
            for (int s = 0; s < DS; s++) {
                const float dA = __expf(dv * A[s]);
                h[s] = fmaf(dA, h[s], dx * bs[s]);
                yv = fmaf(h[s], cs[s], yv);
            }
            dp[(size_t)i * DI] = yv;
        }
    }
}

// ---------------------------------------------------------------------------
// Fused LayerNorm + xc*D residual + silu(z) gate. y fp32 in, yb bf16 out.
// Wave-level __shfl reduce (1 barrier), float4/short8 IO.
// ---------------------------------------------------------------------------
__global__ __launch_bounds__(256)
void ln_fuse(const float* __restrict__ y, const unsigned short* __restrict__ xcb,
             const unsigned short* __restrict__ zb, const float* __restrict__ g,
             const float* __restrict__ bln, const float* __restrict__ Dp,
             unsigned short* __restrict__ yb)
{
    __shared__ float pS[4], pSS[4];
    const int bt   = blockIdx.x;
    const int tid  = threadIdx.x;
    const int lane = tid & 63;
    const int wv   = tid >> 6;
    const float4* yr4 = (const float4*)(y + (size_t)bt * DI);
    const unsigned short* xr = xcb + (size_t)bt * DI;
    const unsigned short* zr = zb + (size_t)bt * DI;
    unsigned short* orow = yb + (size_t)bt * DI;

    float4 a = yr4[tid * 2];
    float4 b4 = yr4[tid * 2 + 1];
    float v[8] = {a.x, a.y, a.z, a.w, b4.x, b4.y, b4.z, b4.w};
    float s = 0.f, ss = 0.f;
#pragma unroll
    for (int j = 0; j < 8; j++) { s += v[j]; ss += v[j] * v[j]; }
#pragma unroll
    for (int off = 32; off > 0; off >>= 1) {
        s  += __shfl_down(s, off);
        ss += __shfl_down(ss, off);
    }
    if (lane == 0) { pS[wv] = s; pSS[wv] = ss; }
    __syncthreads();
    const float S  = pS[0] + pS[1] + pS[2] + pS[3];
    const float SS = pSS[0] + pSS[1] + pSS[2] + pSS[3];
    const float mu   = S * (1.f / DI);
    const float var  = SS * (1.f / DI) - mu * mu;
    const float rstd = rsqrtf(var + 1e-5f);

    const int d0 = tid * 8;
    float4 g0 = ((const float4*)g)[tid * 2],   g1 = ((const float4*)g)[tid * 2 + 1];
    float4 l0 = ((const float4*)bln)[tid * 2], l1 = ((const float4*)bln)[tid * 2 + 1];
    float4 D0 = ((const float4*)Dp)[tid * 2],  D1 = ((const float4*)Dp)[tid * 2 + 1];
    const float gg[8] = {g0.x, g0.y, g0.z, g0.w, g1.x, g1.y, g1.z, g1.w};
    const float ll[8] = {l0.x, l0.y, l0.z, l0.w, l1.x, l1.y, l1.z, l1.w};
    const float DD[8] = {D0.x, D0.y, D0.z, D0.w, D1.x, D1.y, D1.z, D1.w};
    short8 xv = *(const short8*)(xr + d0);
    short8 zv = *(const short8*)(zr + d0);
    short8 o;
#pragma unroll
    for (int j = 0; j < 8; j++) {
        float yn = (v[j] - mu) * rstd * gg[j] + ll[j];
        yn += b2f((unsigned short)xv[j]) * DD[j];
        yn *= siluf(b2f((unsigned short)zv[j]));
        o[j] = (short)f2b(yn);
    }
    *(short8*)(orow + d0) = o;
}

// ---------------------------------------------------------------------------
// Workspace layout (MiB offsets, total ~175 MiB):
//   [  0, 32)  xpb bf16  (G1 out) -> dead after conv -> yb bf16 (ln out)
//   [ 32, 64)  zb  bf16
//   [ 64, 96)  xcb bf16
//   [ 96,160)  dts fp32 (G3 out) -> y fp32 (scan, in-place)
//       [ 96,112) xb bf16   (dead before G3 writes dts)
//       [112,120) W_inb bf16 (dead before G3)
//   [160,170)  Wcb bf16 (2304x2048: W_dt | W_x | zeros) = 9.44 MiB
//   [170,174)  W_outb bf16
//   [174,175)  Bp, Cp fp32
// ---------------------------------------------------------------------------
extern "C" void kernel_launch(void* const* d_in, const int* in_sizes, int n_in,
                              void* d_out, int out_size, void* d_ws, size_t ws_size,
                              hipStream_t stream)
{
    const float* x      = (const float*)d_in[0];
    const float* W_in   = (const float*)d_in[1];
    const float* conv_w = (const float*)d_in[2];
    const float* conv_b = (const float*)d_in[3];
    const float* W_x    = (const float*)d_in[4];
    const float* W_dt   = (const float*)d_in[5];
    const float* b_dt   = (const float*)d_in[6];
    const float* A_log  = (const float*)d_in[7];
    const float* D_par  = (const float*)d_in[8];
    const float* W_out  = (const float*)d_in[9];
    const float* ln_g   = (const float*)d_in[10];
    const float* ln_b   = (const float*)d_in[11];
    float* out = (float*)d_out;

    char* w = (char*)d_ws;
    const size_t MB = 1ull << 20;
    unsigned short* xpb    = (unsigned short*)(w);
    unsigned short* zb     = (unsigned short*)(w + 32 * MB);
    unsigned short* xcb    = (unsigned short*)(w + 64 * MB);
    float*          dts    = (float*)(w + 96 * MB);
    unsigned short* xb     = (unsigned short*)(w + 96 * MB);
    unsigned short* W_inb  = (unsigned short*)(w + 112 * MB);
    unsigned short* Wcb    = (unsigned short*)(w + 160 * MB);
    unsigned short* W_outb = (unsigned short*)(w + 170 * MB);
    float*          BpF    = (float*)(w + 174 * MB);
    float*          CpF    = BpF + (size_t)BT * DS;
    unsigned short* yb     = xpb;   // reuse after conv

    dim3 blk(256);
    dim3 blk512(512);

    // merged conversions to bf16 (one launch)
    cvt_all<<<dim3((N4_TOT + 255) / 256), blk, 0, stream>>>(
        x, xb, W_in, W_inb, W_out, W_outb, W_dt, W_x, Wcb);

    // 1) xz = x @ W_in^T -> split bf16 xpb | zb  (256^2: grid 32x16=512)
    gemm_mfma256<<<dim3((BT / 256) * (2 * DI / 256)), blk512, 0, stream>>>(
        xb, W_inb, BT, 2 * DI, DM, 0, nullptr, xpb, zb, nullptr);

    // 2) depthwise conv + silu -> xcb bf16  (one block per (b,t) row)
    conv_silu<<<dim3(BT), blk, 0, stream>>>(xpb, conv_w, conv_b, xcb);

    // 3) fused dt+ssm GEMM (256^2: grid 32x9=288) -> dts fp32, Bp, Cp
    gemm_mfma256<<<dim3((BT / 256) * (NC / 256)), blk512, 0, stream>>>(
        xcb, Wcb, BT, NC, DI, 1, b_dt, dts, BpF, CpF);

    // 4) chunked parallel scan -> y fp32 (in-place over dts)
    scan2<<<dim3(DI / 16, B_SZ), blk, 0, stream>>>(xcb, dts, BpF, CpF, A_log);

    // 5) LayerNorm + residual + gate -> yb bf16
    ln_fuse<<<dim3(BT), blk, 0, stream>>>(dts, xcb, zb, ln_g, ln_b, D_par, yb);

    // 6) out = y @ W_out^T -> fp32 (128^2 kernel: N=1024 keeps 512 blocks)
    gemm_mfma<<<dim3((BT / 128) * (DM / 128)), blk512, 0, stream>>>(
        yb, W_outb, BT, DM, DI, 2, nullptr, out, nullptr, nullptr);
}

// Round 10
// 617.625 us; speedup vs baseline: 2.3230x; 1.1319x over previous
//
#include <hip/hip_runtime.h>
#include <hip/hip_bf16.h>
#include <math.h>
#include <stdint.h>

// Problem constants (SelectiveSSM: D_MODEL=1024, D_STATE=16, D_CONV=4, EXPAND=2)
#define B_SZ 4
#define T_SZ 2048
#define DM   1024
#define DI   2048          // D_INNER
#define DS   16            // D_STATE
#define BT   (B_SZ*T_SZ)   // 8192
#define NC   2176          // padded N for fused dt+ssm GEMM (17 x 128)

typedef __attribute__((ext_vector_type(8))) short short8;
typedef __attribute__((ext_vector_type(4))) float f32x4;

__device__ __forceinline__ float siluf(float v) { return v / (1.f + __expf(-v)); }
__device__ __forceinline__ float softplusf(float x) {
    return fmaxf(x, 0.f) + log1pf(__expf(-fabsf(x)));
}
__device__ __forceinline__ unsigned short f2b(float f) {
    __hip_bfloat16 h = __float2bfloat16(f);
    return *reinterpret_cast<unsigned short*>(&h);
}
__device__ __forceinline__ float b2f(unsigned short u) {
    unsigned v = (unsigned)u << 16;
    float f;
    __builtin_memcpy(&f, &v, 4);
    return f;
}
__device__ __forceinline__ void gld_lds16(const void* g, void* l) {
    __builtin_amdgcn_global_load_lds(
        (const __attribute__((address_space(1))) unsigned int*)g,
        (__attribute__((address_space(3))) unsigned int*)l,
        16, 0, 0);
}

// ---------------------------------------------------------------------------
// Merged fp32 -> bf16 conversions: x | W_in | W_out plain; W_dt/W_x packed
// into Wcb (2176 x 2048 with zero pad rows 2080..2175). One launch instead
// of four (saves 3 dispatch gaps).
// ---------------------------------------------------------------------------
#define N4_X    (BT * DM / 4)        // 2097152
#define N4_WIN  (2 * DI * DM / 4)    // 1048576
#define N4_WOUT (DM * DI / 4)        // 524288
#define N4_WC   (NC * (DI / 4))      // 1114112
#define N4_TOT  (N4_X + N4_WIN + N4_WOUT + N4_WC)

__global__ __launch_bounds__(256)
void cvt_all(const float* __restrict__ x,   unsigned short* __restrict__ xb,
             const float* __restrict__ Win, unsigned short* __restrict__ Winb,
             const float* __restrict__ Wout,unsigned short* __restrict__ Woutb,
             const float* __restrict__ Wdt, const float* __restrict__ Wx,
             unsigned short* __restrict__ Wcb)
{
    int i = blockIdx.x * 256 + threadIdx.x;
    if (i >= N4_TOT) return;
    float4 v;
    ushort4* dst;
    if (i < N4_X) {
        v = ((const float4*)x)[i];
        dst = (ushort4*)xb + i;
    } else if (i < N4_X + N4_WIN) {
        const int j = i - N4_X;
        v = ((const float4*)Win)[j];
        dst = (ushort4*)Winb + j;
    } else if (i < N4_X + N4_WIN + N4_WOUT) {
        const int j = i - (N4_X + N4_WIN);
        v = ((const float4*)Wout)[j];
        dst = (ushort4*)Woutb + j;
    } else {
        const int j = i - (N4_X + N4_WIN + N4_WOUT);
        const int row = j >> 9;            // / (2048/4)
        const int c4  = j & 511;
        if (row < 2048)      v = ((const float4*)Wdt)[(size_t)row * 512 + c4];
        else if (row < 2080) v = ((const float4*)Wx)[(size_t)(row - 2048) * 512 + c4];
        else                 v = make_float4(0.f, 0.f, 0.f, 0.f);
        dst = (ushort4*)Wcb + j;
    }
    ushort4 o;
    o.x = f2b(v.x); o.y = f2b(v.y); o.z = f2b(v.z); o.w = f2b(v.w);
    *dst = o;
}

// ---------------------------------------------------------------------------
// bf16 MFMA GEMM (v5, verified session-best): C[m,n] = sum_k A[m,k]*B[n,k].
// 128x128 tile, 512 threads (8 waves, 2x4 grid, 64x32 wave-tile), BK=32,
// LDS DOUBLE-BUFFER with ONE barrier per K-iter: prefetch (global_load_lds)
// for iter k+1 issued BEFORE the MFMA phase of iter k.
// LDS XOR swizzle (verified conflicts 1.34e7 -> 0): rows 64B; involution on
// the 16B granule  phys = l ^ (((l>>7)&3)<<4). global_load_lds dest LINEAR;
// global source granule inverse-swizzled  sgran = (tid&3)^((tid>>3)&3).
// Session record: every deeper-pipeline / larger-tile restructure (ring-3
// counted-vmcnt, BK=64, 256x128, 256x256 w/ and w/o spill) was null or a
// regression; this 2-phase 128^2 config is the verified optimum.
// mode 0: bf16 split store  cols<2048 -> o0, else -> o1 (both ldc 2048)
// mode 1: cols<2048 -> softplus(v+bias[col]) fp32 o0 (ldc 2048);
//         2048..2063 -> o1[row*16+c]; 2064..2079 -> o2[row*16+c]; >=2080 drop
// mode 2: fp32 plain store to o0, ldc = N
// ---------------------------------------------------------------------------
__global__ __launch_bounds__(512)
void gemm_mfma(const unsigned short* __restrict__ A,
               const unsigned short* __restrict__ Bm,
               int M, int N, int K, int mode,
               const float* __restrict__ bias,
               void* __restrict__ o0, void* __restrict__ o1, void* __restrict__ o2)
{
    __shared__ unsigned short As[2][128 * 32];   // 2 x 8 KB
    __shared__ unsigned short Bs[2][128 * 32];   // 2 x 8 KB

    // GROUP_M swizzle (GM=16 divides npm=64 for all three GEMMs here)
    const int npn = N >> 7;
    const int pid = blockIdx.x;
    const int gsz = 16 * npn;
    const int gid = pid / gsz;
    const int pm  = gid * 16 + (pid % 16);
    const int pn  = (pid % gsz) / 16;
    const int bm  = pm * 128;
    const int bn  = pn * 128;

    const int tid  = threadIdx.x;
    const int lane = tid & 63;
    const int wave = tid >> 6;          // 0..7
    const int wm   = (wave >> 2) * 64;  // {0,64}
    const int wn   = (wave & 3) * 32;   // {0,32,64,96}

    f32x4 zero4 = {0.f, 0.f, 0.f, 0.f};
    f32x4 acc[4][2];
#pragma unroll
    for (int i = 0; i < 4; i++)
#pragma unroll
        for (int j = 0; j < 2; j++) acc[i][j] = zero4;

    // staging: 512 threads x 16B = one full 128x32 bf16 tile per matrix.
    // LDS dest linear: thread tid -> row tid>>2, slot tid&3. Source granule
    // inverse-swizzled so that swizzled reads see logical data (rule #21).
    const int sr    = tid >> 2;                      // 0..127
    const int sgran = (tid & 3) ^ ((tid >> 3) & 3);  // inverse of read swizzle
    const unsigned short* Ag = A  + (size_t)(bm + sr) * K + sgran * 8;
    const unsigned short* Bg = Bm + (size_t)(bn + sr) * K + sgran * 8;

    // per-lane swizzled read byte-offsets for the 6 fragments
    const int fr = lane & 15;          // row within 16-tile
    const int fg = lane >> 4;          // 16B k-granule 0..3
    int aoff[4], boff[2];
#pragma unroll
    for (int i = 0; i < 4; i++) {
        const int l = (wm + i * 16 + fr) * 64 + fg * 16;
        aoff[i] = l ^ (((l >> 7) & 3) << 4);
    }
#pragma unroll
    for (int j = 0; j < 2; j++) {
        const int l = (wn + j * 16 + fr) * 64 + fg * 16;
        boff[j] = l ^ (((l >> 7) & 3) << 4);
    }

    // prologue: stage k=0 into buf 0
    gld_lds16(Ag, &As[0][tid * 8]);
    gld_lds16(Bg, &Bs[0][tid * 8]);
    __syncthreads();

    int cur = 0;
    for (int k0 = 0; k0 < K; k0 += 32) {
        // prefetch next tile into the other buffer (async, drains at barrier)
        if (k0 + 32 < K) {
            gld_lds16(Ag + k0 + 32, &As[cur ^ 1][tid * 8]);
            gld_lds16(Bg + k0 + 32, &Bs[cur ^ 1][tid * 8]);
        }
        const char* Ab = (const char*)&As[cur][0];
        const char* Bb = (const char*)&Bs[cur][0];
        short8 af[4], bf[2];
#pragma unroll
        for (int i = 0; i < 4; i++)
            af[i] = *(const short8*)(Ab + aoff[i]);
#pragma unroll
        for (int j = 0; j < 2; j++)
            bf[j] = *(const short8*)(Bb + boff[j]);
#pragma unroll
        for (int i = 0; i < 4; i++)
#pragma unroll
            for (int j = 0; j < 2; j++)
                acc[i][j] = __builtin_amdgcn_mfma_f32_16x16x32_bf16(
                    af[i], bf[j], acc[i][j], 0, 0, 0);
        __syncthreads();   // waits prefetch (vmcnt) + all reads of cur done
        cur ^= 1;
    }

    // epilogue. C/D layout: col = lane&15, row = (lane>>4)*4 + r  [m89/m91]
    const int cr0 = bm + wm + (lane >> 4) * 4;
    const int cc0 = bn + wn + (lane & 15);
#pragma unroll
    for (int i = 0; i < 4; i++) {
#pragma unroll
        for (int j = 0; j < 2; j++) {
            const int col = cc0 + j * 16;
#pragma unroll
            for (int r = 0; r < 4; r++) {
                const int row = cr0 + i * 16 + r;
                float v = acc[i][j][r];
                if (mode == 0) {
                    if (col < 2048)
                        ((unsigned short*)o0)[(size_t)row * 2048 + col] = f2b(v);
                    else
                        ((unsigned short*)o1)[(size_t)row * 2048 + col - 2048] = f2b(v);
                } else if (mode == 1) {
                    if (col < 2048) {
                        ((float*)o0)[(size_t)row * 2048 + col] = softplusf(v + bias[col]);
                    } else if (col < 2064) {
                        ((float*)o1)[(size_t)row * DS + (col - 2048)] = v;
                    } else if (col < 2080) {
                        ((float*)o2)[(size_t)row * DS + (col - 2064)] = v;
                    }
                } else {
                    ((float*)o0)[(size_t)row * N + col] = v;
                }
            }
        }
    }
}

// ---------------------------------------------------------------------------
// Depthwise causal conv (width 4) + SiLU, bf16 in -> bf16 out.
// Vectorized 8 channels/thread (short8 loads, G13). One block = one (b,t)
// row (256 thr x 8 ch = 2048 = DI), so tap guards are uniform.
// ---------------------------------------------------------------------------
__global__ __launch_bounds__(256)
void conv_silu(const unsigned short* __restrict__ xpb, const float* __restrict__ cw,
               const float* __restrict__ cb, unsigned short* __restrict__ xcb)
{
    const int bt  = blockIdx.x;            // 0..BT-1
    const int t   = bt & (T_SZ - 1);
    const int i0  = threadIdx.x * 8;       // channel group base

    float acc[8];
    {
        float4 c0 = ((const float4*)cb)[threadIdx.x * 2];
        float4 c1 = ((const float4*)cb)[threadIdx.x * 2 + 1];
        acc[0]=c0.x; acc[1]=c0.y; acc[2]=c0.z; acc[3]=c0.w;
        acc[4]=c1.x; acc[5]=c1.y; acc[6]=c1.z; acc[7]=c1.w;
    }
    float4 w[8];
#pragma unroll
    for (int c = 0; c < 8; c++) w[c] = ((const float4*)cw)[i0 + c];

#pragma unroll
    for (int k = 0; k < 4; k++) {
        const int tt = t - 3 + k;          // uniform across block
        if (tt >= 0) {
            short8 xv = *(const short8*)(xpb + (size_t)(bt - 3 + k) * DI + i0);
#pragma unroll
            for (int c = 0; c < 8; c++)
                acc[c] = fmaf(b2f((unsigned short)xv[c]), ((const float*)&w[c])[k], acc[c]);
        }
    }
    short8 o;
#pragma unroll
    for (int c = 0; c < 8; c++) o[c] = (short)f2b(siluf(acc[c]));
    *(short8*)(xcb + (size_t)bt * DI + i0) = o;
}

// ---------------------------------------------------------------------------
// Chunked parallel selective scan. Block: 16 chunks x 16 d-cols = 256 thr.
// Grid: (DI/16, B). Phase1: per-chunk (h_end, prod dA) from h0=0.
// Phase2: LDS carry combine. Phase3: replay with corrected h0, y in-place.
// FAST PATH: A[s] = -(s+1)/2 (this problem's A_log) -> exp(dv*A[s]) =
// r^(s+1), r = exp(-dv/2): 1 exp + 15 muls. Runtime-checked, general
// fallback kept.
// ---------------------------------------------------------------------------
#define CH 16
#define CL (T_SZ / CH)   // 128

__global__ __launch_bounds__(256)
void scan2(const unsigned short* __restrict__ xcb, float* __restrict__ dty,
           const float* __restrict__ Bp, const float* __restrict__ Cp,
           const float* __restrict__ A_log)
{
    __shared__ float shH[CH][16][DS];
    __shared__ float shP[CH][16][DS];
    __shared__ float shI[CH][16][DS];
    const int tid = threadIdx.x;
    const int c = tid >> 4;
    const int g = tid & 15;
    const int b = blockIdx.y;
    const int d = blockIdx.x * 16 + g;

    float A[DS];
    bool structured = true;
#pragma unroll
    for (int s = 0; s < DS; s++) {
        A[s] = -__expf(A_log[s]);
        structured = structured && (fabsf(A[s] + 0.5f * (float)(s + 1)) <= 1e-4f);
    }

    const size_t colbase = (size_t)b * T_SZ * DI + d;
    const unsigned short* xp = xcb + colbase + (size_t)c * CL * DI;
    float* dp = dty + colbase + (size_t)c * CL * DI;
    const float4* Bb = (const float4*)(Bp + ((size_t)b * T_SZ + c * CL) * DS);
    const float4* Cb = (const float4*)(Cp + ((size_t)b * T_SZ + c * CL) * DS);

    float h[DS];
    float sdv = 0.f;
#pragma unroll
    for (int s = 0; s < DS; s++) h[s] = 0.f;

    if (structured) {
        for (int i = 0; i < CL; i++) {
            const float xv = b2f(xp[(size_t)i * DI]);
            const float dv = dp[(size_t)i * DI];
            float4 Bv[4] = {Bb[i*4+0], Bb[i*4+1], Bb[i*4+2], Bb[i*4+3]};
            const float* bs = (const float*)&Bv[0];
            const float dx = dv * xv;
            sdv += dv;
            const float r = __expf(-0.5f * dv);
            float dA = r;
#pragma unroll
            for (int s = 0; s < DS; s++) {
                h[s] = fmaf(dA, h[s], dx * bs[s]);
                dA *= r;
            }
        }
    } else {
        for (int i = 0; i < CL; i++) {
            const float xv = b2f(xp[(size_t)i * DI]);
            const float dv = dp[(size_t)i * DI];
            float4 Bv[4] = {Bb[i*4+0], Bb[i*4+1], Bb[i*4+2], Bb[i*4+3]};
            const float* bs = (const float*)&Bv[0];
            const float dx = dv * xv;
            sdv += dv;
#pragma unroll
            for (int s = 0; s < DS; s++) {
                const float dA = __expf(dv * A[s]);
                h[s] = fmaf(dA, h[s], dx * bs[s]);
            }
        }
    }

    {
        float P[DS];
        if (structured) {
            const float R = __expf(-0.5f * sdv);
            float p = 1.f;
#pragma unroll
            for (int s = 0; s < DS; s++) { p *= R; P[s] = p; }
        } else {
#pragma unroll
            for (int s = 0; s < DS; s++) P[s] = __expf(sdv * A[s]);
        }
#pragma unroll
        for (int s = 0; s < DS; s += 4) {
            *(float4*)&shH[c][g][s] = make_float4(h[s], h[s+1], h[s+2], h[s+3]);
            *(float4*)&shP[c][g][s] = make_float4(P[s], P[s+1], P[s+2], P[s+3]);
        }
    }
    __syncthreads();

    {
        const int g2 = tid >> 4, s2 = tid & 15;
        float hin = 0.f;
        shI[0][g2][s2] = 0.f;
        for (int cc = 1; cc < CH; cc++) {
            hin = fmaf(shP[cc-1][g2][s2], hin, shH[cc-1][g2][s2]);
            shI[cc][g2][s2] = hin;
        }
    }
    __syncthreads();

#pragma unroll
    for (int s = 0; s < DS; s++) h[s] = shI[c][g][s];

    if (structured) {
        for (int i = 0; i < CL; i++) {
            const float xv = b2f(xp[(size_t)i * DI]);
            const float dv = dp[(size_t)i * DI];
            float4 Bv[4] = {Bb[i*4+0], Bb[i*4+1], Bb[i*4+2], Bb[i*4+3]};
            float4 Cv[4] = {Cb[i*4+0], Cb[i*4+1], Cb[i*4+2], Cb[i*4+3]};
            const float* bs = (const float*)&Bv[0];
            const float* cs = (const float*)&Cv[0];
            const float dx = dv * xv;
            float yv = 0.f;
            const float r = __expf(-0.5f * dv);
            float dA = r;
#pragma unroll
            for (int s = 0; s < DS; s++) {
                h[s] = fmaf(dA, h[s], dx * bs[s]);
                yv = fmaf(h[s], cs[s], yv);
                dA *= r;
            }
            dp[(size_t)i * DI] = yv;   // overwrites dt[t] after its last use
        }
    } else {
        for (int i = 0; i < CL; i++) {
            const float xv = b2f(xp[(size_t)i * DI]);
            const float dv = dp[(size_t)i * DI];
            float4 Bv[4] = {Bb[i*4+0], Bb[i*4+1], Bb[i*4+2], Bb[i*4+3]};
            float4 Cv[4] = {Cb[i*4+0], Cb[i*4+1], Cb[i*4+2], Cb[i*4+3]};
            const float* bs = (const float*)&Bv[0];
            const float* cs = (const float*)&Cv[0];
            const float dx = dv * xv;
            float yv = 0.f;
#pragma unroll
            for (int s = 0; s < DS; s++) {
                const float dA = __expf(dv * A[s]);
                h[s] = fmaf(dA, h[s], dx * bs[s]);
                yv = fmaf(h[s], cs[s], yv);
            }
            dp[(size_t)i * DI] = yv;
        }
    }
}

// ---------------------------------------------------------------------------
// Fused LayerNorm + xc*D residual + silu(z) gate. y fp32 in, yb bf16 out.
// Wave-level __shfl reduce (1 barrier), float4/short8 IO.
// ---------------------------------------------------------------------------
__global__ __launch_bounds__(256)
void ln_fuse(const float* __restrict__ y, const unsigned short* __restrict__ xcb,
             const unsigned short* __restrict__ zb, const float* __restrict__ g,
             const float* __restrict__ bln, const float* __restrict__ Dp,
             unsigned short* __restrict__ yb)
{
    __shared__ float pS[4], pSS[4];
    const int bt   = blockIdx.x;
    const int tid  = threadIdx.x;
    const int lane = tid & 63;
    const int wv   = tid >> 6;
    const float4* yr4 = (const float4*)(y + (size_t)bt * DI);
    const unsigned short* xr = xcb + (size_t)bt * DI;
    const unsigned short* zr = zb + (size_t)bt * DI;
    unsigned short* orow = yb + (size_t)bt * DI;

    float4 a = yr4[tid * 2];
    float4 b4 = yr4[tid * 2 + 1];
    float v[8] = {a.x, a.y, a.z, a.w, b4.x, b4.y, b4.z, b4.w};
    float s = 0.f, ss = 0.f;
#pragma unroll
    for (int j = 0; j < 8; j++) { s += v[j]; ss += v[j] * v[j]; }
#pragma unroll
    for (int off = 32; off > 0; off >>= 1) {
        s  += __shfl_down(s, off);
        ss += __shfl_down(ss, off);
    }
    if (lane == 0) { pS[wv] = s; pSS[wv] = ss; }
    __syncthreads();
    const float S  = pS[0] + pS[1] + pS[2] + pS[3];
    const float SS = pSS[0] + pSS[1] + pSS[2] + pSS[3];
    const float mu   = S * (1.f / DI);
    const float var  = SS * (1.f / DI) - mu * mu;
    const float rstd = rsqrtf(var + 1e-5f);

    const int d0 = tid * 8;
    float4 g0 = ((const float4*)g)[tid * 2],   g1 = ((const float4*)g)[tid * 2 + 1];
    float4 l0 = ((const float4*)bln)[tid * 2], l1 = ((const float4*)bln)[tid * 2 + 1];
    float4 D0 = ((const float4*)Dp)[tid * 2],  D1 = ((const float4*)Dp)[tid * 2 + 1];
    const float gg[8] = {g0.x, g0.y, g0.z, g0.w, g1.x, g1.y, g1.z, g1.w};
    const float ll[8] = {l0.x, l0.y, l0.z, l0.w, l1.x, l1.y, l1.z, l1.w};
    const float DD[8] = {D0.x, D0.y, D0.z, D0.w, D1.x, D1.y, D1.z, D1.w};
    short8 xv = *(const short8*)(xr + d0);
    short8 zv = *(const short8*)(zr + d0);
    short8 o;
#pragma unroll
    for (int j = 0; j < 8; j++) {
        float yn = (v[j] - mu) * rstd * gg[j] + ll[j];
        yn += b2f((unsigned short)xv[j]) * DD[j];
        yn *= siluf(b2f((unsigned short)zv[j]));
        o[j] = (short)f2b(yn);
    }
    *(short8*)(orow + d0) = o;
}

// ---------------------------------------------------------------------------
// Workspace layout (MiB offsets, total ~175 MiB):
//   [  0, 32)  xpb bf16  (G1 out) -> dead after conv -> yb bf16 (ln out)
//   [ 32, 64)  zb  bf16
//   [ 64, 96)  xcb bf16
//   [ 96,160)  dts fp32 (G3 out) -> y fp32 (scan, in-place)
//       [ 96,112) xb bf16   (dead before G3 writes dts)
//       [112,120) W_inb bf16 (dead before G3)
//   [160,169)  Wcb bf16 (2176x2048: W_dt | W_x | zeros)
//   [169,173)  W_outb bf16
//   [174,175)  Bp, Cp fp32
// ---------------------------------------------------------------------------
extern "C" void kernel_launch(void* const* d_in, const int* in_sizes, int n_in,
                              void* d_out, int out_size, void* d_ws, size_t ws_size,
                              hipStream_t stream)
{
    const float* x      = (const float*)d_in[0];
    const float* W_in   = (const float*)d_in[1];
    const float* conv_w = (const float*)d_in[2];
    const float* conv_b = (const float*)d_in[3];
    const float* W_x    = (const float*)d_in[4];
    const float* W_dt   = (const float*)d_in[5];
    const float* b_dt   = (const float*)d_in[6];
    const float* A_log  = (const float*)d_in[7];
    const float* D_par  = (const float*)d_in[8];
    const float* W_out  = (const float*)d_in[9];
    const float* ln_g   = (const float*)d_in[10];
    const float* ln_b   = (const float*)d_in[11];
    float* out = (float*)d_out;

    char* w = (char*)d_ws;
    const size_t MB = 1ull << 20;
    unsigned short* xpb    = (unsigned short*)(w);
    unsigned short* zb     = (unsigned short*)(w + 32 * MB);
    unsigned short* xcb    = (unsigned short*)(w + 64 * MB);
    float*          dts    = (float*)(w + 96 * MB);
    unsigned short* xb     = (unsigned short*)(w + 96 * MB);
    unsigned short* W_inb  = (unsigned short*)(w + 112 * MB);
    unsigned short* Wcb    = (unsigned short*)(w + 160 * MB);
    unsigned short* W_outb = (unsigned short*)(w + 169 * MB);
    float*          BpF    = (float*)(w + 174 * MB);
    float*          CpF    = BpF + (size_t)BT * DS;
    unsigned short* yb     = xpb;   // reuse after conv

    dim3 blk(256);
    dim3 blk512(512);

    // merged conversions to bf16 (one launch)
    cvt_all<<<dim3((N4_TOT + 255) / 256), blk, 0, stream>>>(
        x, xb, W_in, W_inb, W_out, W_outb, W_dt, W_x, Wcb);

    // 1) xz = x @ W_in^T -> split bf16 xpb | zb
    gemm_mfma<<<dim3((BT / 128) * (2 * DI / 128)), blk512, 0, stream>>>(
        xb, W_inb, BT, 2 * DI, DM, 0, nullptr, xpb, zb, nullptr);

    // 2) depthwise conv + silu -> xcb bf16  (one block per (b,t) row)
    conv_silu<<<dim3(BT), blk, 0, stream>>>(xpb, conv_w, conv_b, xcb);

    // 3) fused dt+ssm GEMM: [W_dt | W_x] -> dts fp32 (softplus+bias), Bp, Cp
    gemm_mfma<<<dim3((BT / 128) * (NC / 128)), blk512, 0, stream>>>(
        xcb, Wcb, BT, NC, DI, 1, b_dt, dts, BpF, CpF);

    // 4) chunked parallel scan -> y fp32 (in-place over dts)
    scan2<<<dim3(DI / 16, B_SZ), blk, 0, stream>>>(xcb, dts, BpF, CpF, A_log);

    // 5) LayerNorm + residual + gate -> yb bf16
    ln_fuse<<<dim3(BT), blk, 0, stream>>>(dts, xcb, zb, ln_g, ln_b, D_par, yb);

    // 6) out = y @ W_out^T -> fp32
    gemm_mfma<<<dim3((BT / 128) * (DM / 128)), blk512, 0, stream>>>(
        yb, W_outb, BT, DM, DI, 2, nullptr, out, nullptr, nullptr);
}